// Round 3
// baseline (233.546 us; speedup 1.0000x reference)
//
#include <hip/hip_runtime.h>
#include <hip/hip_bf16.h>
#include <math.h>

// BertSelfAttention on MI355X (gfx950).
// S=2048, H=1024, 16 heads, hd=64. fp32 in/out, bf16x3-split MFMA compute.
//
// R2 changes vs R1:
//  - attn: KBLK 64->32, LDS 73->37KB => 4 blocks/CU (was 2); setprio around MFMA;
//          defer-max (THR=8); proper 2-way-free V-tile swizzle ((d>>1)&3).
//  - qkv GEMM: 128x128 tile (4x4 acc/wave, m97 geometry); proj: 64x128 (256 blocks).
//  - GEMM LDS fragment reads swizzled (pre-swizzled global src), 2-way-free.
//
#define MB(x) ((size_t)(x) << 20)
static constexpr size_t O_XHI = MB(0),  O_XLO = MB(4);
static constexpr size_t O_WQH = MB(8),  O_WQL = MB(10);
static constexpr size_t O_WKH = MB(12), O_WKL = MB(14);
static constexpr size_t O_WVH = MB(16), O_WVL = MB(18);
static constexpr size_t O_WOH = MB(20), O_WOL = MB(22);
static constexpr size_t O_QHI = MB(24), O_QLO = MB(28);
static constexpr size_t O_KHI = MB(32), O_KLO = MB(36);
static constexpr size_t O_VTH = MB(40), O_VTL = MB(44);  // V^T [1024][2048]
static constexpr size_t O_CXH = MB(48), O_CXL = MB(52);

typedef __bf16 bf16x8 __attribute__((ext_vector_type(8)));
typedef __bf16 bf16x4 __attribute__((ext_vector_type(4)));
typedef float  f32x4  __attribute__((ext_vector_type(4)));

#define MFMA(a, b, c) __builtin_amdgcn_mfma_f32_16x16x32_bf16(a, b, c, 0, 0, 0)

__device__ __forceinline__ void g2l16(const void* g, void* l) {
  __builtin_amdgcn_global_load_lds(
      (const __attribute__((address_space(1))) unsigned int*)g,
      (__attribute__((address_space(3))) unsigned int*)l, 16, 0, 0);
}

// ---------------- 1. elementwise hi/lo split (x) ----------------
__global__ __launch_bounds__(256) void split_kernel(
    const float* __restrict__ s, __bf16* __restrict__ hi, __bf16* __restrict__ lo) {
  int i = blockIdx.x * 256 + threadIdx.x;
  float4 v = reinterpret_cast<const float4*>(s)[i];
  float vv[4] = {v.x, v.y, v.z, v.w};
  bf16x4 h, l;
#pragma unroll
  for (int j = 0; j < 4; ++j) {
    __bf16 hb = (__bf16)vv[j];
    h[j] = hb;
    l[j] = (__bf16)(vv[j] - (float)hb);
  }
  reinterpret_cast<bf16x4*>(hi)[i] = h;
  reinterpret_cast<bf16x4*>(lo)[i] = l;
}

// ---------------- 2. transpose + hi/lo split (4 weights, 1024x1024) ----------------
__global__ __launch_bounds__(256) void tsplit_kernel(
    char* __restrict__ ws, const float* __restrict__ W0, const float* __restrict__ W1,
    const float* __restrict__ W2, const float* __restrict__ W3) {
  const float* srcs[4] = {W0, W1, W2, W3};
  const size_t hofs[4] = {O_WQH, O_WKH, O_WVH, O_WOH};
  const size_t lofs[4] = {O_WQL, O_WKL, O_WVL, O_WOL};
  int z = blockIdx.z;
  const float* s = srcs[z];
  __bf16* thi = (__bf16*)(ws + hofs[z]);
  __bf16* tlo = (__bf16*)(ws + lofs[z]);
  __shared__ float tile[32][33];
  int tx = threadIdx.x & 31, ty = threadIdx.x >> 5;  // 32x8
  int r0 = blockIdx.y * 32, c0 = blockIdx.x * 32;
#pragma unroll
  for (int j = 0; j < 32; j += 8)
    tile[ty + j][tx] = s[(size_t)(r0 + ty + j) * 1024 + c0 + tx];
  __syncthreads();
#pragma unroll
  for (int j = 0; j < 32; j += 8) {
    float v = tile[tx][ty + j];
    __bf16 hb = (__bf16)v;
    size_t o = (size_t)(c0 + ty + j) * 1024 + r0 + tx;  // out[c][r] = in[r][c]
    thi[o] = hb;
    tlo[o] = (__bf16)(v - (float)hb);
  }
}

// ---------------- GEMM core: C[M,N] = A[M,1024] @ Bt[N,1024]^T + bias ----------------
// BK=32, 256 threads = 4 waves (2x2), double-buffered, bf16x3.
// Buffer layout (elems): sAh=0 [BM][32], sAl=BM*32, sBh=BM*64 [BN][32], sBl=BM*64+BN*32.
// LDS 16B-seg swizzle: LDS[row][seg s] holds global seg s^((row>>1)&3)  (2-way-free).
template <int BM, int BN>
__device__ __forceinline__ void stage_gemm(
    const __bf16* __restrict__ Ahi, const __bf16* __restrict__ Alo,
    const __bf16* __restrict__ Bth, const __bf16* __restrict__ Btl,
    __bf16* buf, int t, size_t abase, size_t bbase, int k0) {
#pragma unroll
  for (int i = 0; i < BM / 64; ++i) {
    g2l16(Ahi + abase + (size_t)i * 64 * 1024 + k0, buf + i * 2048 + (size_t)t * 8);
    g2l16(Alo + abase + (size_t)i * 64 * 1024 + k0, buf + BM * 32 + i * 2048 + (size_t)t * 8);
  }
#pragma unroll
  for (int i = 0; i < BN / 64; ++i) {
    g2l16(Bth + bbase + (size_t)i * 64 * 1024 + k0, buf + BM * 64 + i * 2048 + (size_t)t * 8);
    g2l16(Btl + bbase + (size_t)i * 64 * 1024 + k0, buf + BM * 64 + BN * 32 + i * 2048 + (size_t)t * 8);
  }
}

template <int BM, int BN, int MODE>
__device__ __forceinline__ void gemm_core(
    __bf16* smem,  // [2][(BM+BN)*64]
    const __bf16* __restrict__ Ahi, const __bf16* __restrict__ Alo,
    const __bf16* __restrict__ Bth, const __bf16* __restrict__ Btl,
    const float* __restrict__ bias, float scale,
    __bf16* __restrict__ Ohi, __bf16* __restrict__ Olo, float* __restrict__ Of,
    int bm, int bn) {
  constexpr int MT = BM / 32, NT = BN / 32;
  constexpr int BUF = (BM + BN) * 64;
  const int t = threadIdx.x;
  const int lane = t & 63, wid = t >> 6;
  const int wm = wid >> 1, wn = wid & 1;
  const int l15 = lane & 15, lq = lane >> 4;

  f32x4 acc[MT][NT];
#pragma unroll
  for (int i = 0; i < MT; ++i)
#pragma unroll
    for (int j = 0; j < NT; ++j) acc[i][j] = f32x4{0.f, 0.f, 0.f, 0.f};

  const int sg = (t & 3) ^ ((t >> 3) & 3);  // pre-swizzled global 16B seg
  const size_t abase = (size_t)(bm * BM + (t >> 2)) * 1024 + sg * 8;
  const size_t bbase = (size_t)(bn * BN + (t >> 2)) * 1024 + sg * 8;

  stage_gemm<BM, BN>(Ahi, Alo, Bth, Btl, smem, t, abase, bbase, 0);
  __syncthreads();

  for (int ks = 0; ks < 32; ++ks) {
    __bf16* cur = smem + (size_t)(ks & 1) * BUF;
    if (ks + 1 < 32)
      stage_gemm<BM, BN>(Ahi, Alo, Bth, Btl, smem + (size_t)((ks + 1) & 1) * BUF,
                         t, abase, bbase, (ks + 1) * 32);

    bf16x8 bh[NT], bl[NT];
#pragma unroll
    for (int nt = 0; nt < NT; ++nt) {
      int row = wn * (NT * 16) + nt * 16 + l15;
      int off = row * 32 + (lq ^ ((row >> 1) & 3)) * 8;
      bh[nt] = *(const bf16x8*)(cur + BM * 64 + off);
      bl[nt] = *(const bf16x8*)(cur + BM * 64 + BN * 32 + off);
    }
#pragma unroll
    for (int mt = 0; mt < MT; ++mt) {
      int row = wm * (MT * 16) + mt * 16 + l15;
      int off = row * 32 + (lq ^ ((row >> 1) & 3)) * 8;
      bf16x8 ah = *(const bf16x8*)(cur + off);
      bf16x8 al = *(const bf16x8*)(cur + BM * 32 + off);
#pragma unroll
      for (int nt = 0; nt < NT; ++nt) {
        acc[mt][nt] = MFMA(ah, bh[nt], acc[mt][nt]);
        acc[mt][nt] = MFMA(al, bh[nt], acc[mt][nt]);
        acc[mt][nt] = MFMA(ah, bl[nt], acc[mt][nt]);
      }
    }
    __syncthreads();
  }

#pragma unroll
  for (int nt = 0; nt < NT; ++nt) {
    int col = bn * BN + wn * (NT * 16) + nt * 16 + l15;
    float bv = bias[col];
#pragma unroll
    for (int mt = 0; mt < MT; ++mt) {
#pragma unroll
      for (int r = 0; r < 4; ++r) {
        int row = bm * BM + wm * (MT * 16) + mt * 16 + lq * 4 + r;
        float v = (acc[mt][nt][r] + bv) * scale;
        if constexpr (MODE == 0) {
          __bf16 hb = (__bf16)v;
          Ohi[(size_t)row * 1024 + col] = hb;
          Olo[(size_t)row * 1024 + col] = (__bf16)(v - (float)hb);
        } else if constexpr (MODE == 1) {
          __bf16 hb = (__bf16)v;
          Ohi[(size_t)col * 2048 + row] = hb;
          Olo[(size_t)col * 2048 + row] = (__bf16)(v - (float)hb);
        } else {
          Of[(size_t)row * 1024 + col] = v;
        }
      }
    }
  }
}

// ---------------- 3. fused QKV (128x128 tiles) ----------------
__global__ __launch_bounds__(256) void qkv_kernel(
    char* __restrict__ ws, const float* __restrict__ bq,
    const float* __restrict__ bk, const float* __restrict__ bv) {
  __shared__ __align__(16) __bf16 smem[2][16384];  // 64 KB
  const __bf16* xhi = (const __bf16*)(ws + O_XHI);
  const __bf16* xlo = (const __bf16*)(ws + O_XLO);
  int bm = blockIdx.x, bn = blockIdx.y;
  if (blockIdx.z == 0) {
    gemm_core<128, 128, 0>(&smem[0][0], xhi, xlo, (const __bf16*)(ws + O_WQH),
                           (const __bf16*)(ws + O_WQL), bq, 0.125f,
                           (__bf16*)(ws + O_QHI), (__bf16*)(ws + O_QLO), nullptr, bm, bn);
  } else if (blockIdx.z == 1) {
    gemm_core<128, 128, 0>(&smem[0][0], xhi, xlo, (const __bf16*)(ws + O_WKH),
                           (const __bf16*)(ws + O_WKL), bk, 1.0f,
                           (__bf16*)(ws + O_KHI), (__bf16*)(ws + O_KLO), nullptr, bm, bn);
  } else {
    gemm_core<128, 128, 1>(&smem[0][0], xhi, xlo, (const __bf16*)(ws + O_WVH),
                           (const __bf16*)(ws + O_WVL), bv, 1.0f,
                           (__bf16*)(ws + O_VTH), (__bf16*)(ws + O_VTL), nullptr, bm, bn);
  }
}

// ---------------- 4. flash attention ----------------
// grid (32 qblocks, 16 heads), 256 thr = 4 waves; wave owns 16 queries; KBLK=32.
// LDS 37KB => 4 blocks/CU. K swizzle: seg^(key&7); V swizzle: seg^((d>>1)&3).
__device__ __forceinline__ void stage_attn(
    const __bf16* __restrict__ Khi, const __bf16* __restrict__ Klo,
    const __bf16* __restrict__ Vth, const __bf16* __restrict__ Vtl,
    __bf16* kh, __bf16* kl, __bf16* vh, __bf16* vl, int t, int h, int kb) {
  const int tr = t >> 3;                 // key row 0..31
  const int sg = (t & 7) ^ (tr & 7);     // pre-swizzled 16B seg (8 segs/row)
  const size_t kg = (size_t)(kb * 32 + tr) * 1024 + h * 64 + sg * 8;
  g2l16(Khi + kg, kh + (size_t)t * 8);
  g2l16(Klo + kg, kl + (size_t)t * 8);
  const int vr = t >> 2;                 // d row 0..63
  const int vs = (t & 3) ^ ((vr >> 1) & 3);  // 4 segs/row
  const size_t vg = (size_t)(h * 64 + vr) * 2048 + kb * 32 + vs * 8;
  g2l16(Vth + vg, vh + (size_t)t * 8);
  g2l16(Vtl + vg, vl + (size_t)t * 8);
}

__global__ __launch_bounds__(256) void attn_kernel(char* __restrict__ ws) {
  __shared__ __align__(16) __bf16 skh[2][2048];  // [buf][32 keys][64 d] swizzled
  __shared__ __align__(16) __bf16 skl[2][2048];
  __shared__ __align__(16) __bf16 svh[2][2048];  // [buf][64 d][32 k] swizzled
  __shared__ __align__(16) __bf16 svl[2][2048];
  __shared__ __align__(16) __bf16 spl[4][640];   // per-wave P[16 q][40] (pad 32->40)

  const __bf16* Qhi = (const __bf16*)(ws + O_QHI);
  const __bf16* Qlo = (const __bf16*)(ws + O_QLO);
  const __bf16* Khi = (const __bf16*)(ws + O_KHI);
  const __bf16* Klo = (const __bf16*)(ws + O_KLO);
  const __bf16* Vth = (const __bf16*)(ws + O_VTH);
  const __bf16* Vtl = (const __bf16*)(ws + O_VTL);
  __bf16* Cxh = (__bf16*)(ws + O_CXH);
  __bf16* Cxl = (__bf16*)(ws + O_CXL);

  const int t = threadIdx.x, lane = t & 63, wid = t >> 6;
  const int l15 = lane & 15, lq = lane >> 4;
  const int h = blockIdx.y;
  const int qbase = blockIdx.x * 64 + wid * 16;

  // Q fragments hoisted (already scaled by 1/8): lane holds Q[q=l15][d=32*dc+8*lq+i]
  bf16x8 qh[2], ql[2];
  {
    const size_t qrow = (size_t)(qbase + l15) * 1024 + h * 64 + lq * 8;
    qh[0] = *(const bf16x8*)(Qhi + qrow);
    qh[1] = *(const bf16x8*)(Qhi + qrow + 32);
    ql[0] = *(const bf16x8*)(Qlo + qrow);
    ql[1] = *(const bf16x8*)(Qlo + qrow + 32);
  }

  f32x4 ctx[4];
#pragma unroll
  for (int i = 0; i < 4; ++i) ctx[i] = f32x4{0.f, 0.f, 0.f, 0.f};
  float m_run = -INFINITY, l_run = 0.f;

  stage_attn(Khi, Klo, Vth, Vtl, skh[0], skl[0], svh[0], svl[0], t, h, 0);
  __syncthreads();

  for (int kb = 0; kb < 64; ++kb) {
    const int cur = kb & 1;
    if (kb + 1 < 64) {
      const int nxt = cur ^ 1;
      stage_attn(Khi, Klo, Vth, Vtl, skh[nxt], skl[nxt], svh[nxt], svl[nxt], t, h, kb + 1);
    }

    // ---- scores S^T [32 keys][16 q], bf16x3 over d=64 (2 chunks) ----
    f32x4 sacc[2];
    __builtin_amdgcn_s_setprio(1);
#pragma unroll
    for (int kt = 0; kt < 2; ++kt) {
      sacc[kt] = f32x4{0.f, 0.f, 0.f, 0.f};
#pragma unroll
      for (int dc = 0; dc < 2; ++dc) {
        int key = kt * 16 + l15;
        int off = key * 64 + ((dc * 4 + lq) ^ (key & 7)) * 8;  // swizzled read
        bf16x8 khf = *(const bf16x8*)(&skh[cur][0] + off);
        bf16x8 klf = *(const bf16x8*)(&skl[cur][0] + off);
        sacc[kt] = MFMA(khf, qh[dc], sacc[kt]);
        sacc[kt] = MFMA(klf, qh[dc], sacc[kt]);
        sacc[kt] = MFMA(khf, ql[dc], sacc[kt]);
      }
    }
    __builtin_amdgcn_s_setprio(0);

    // ---- online softmax (defer-max, THR=8): lanes {q,q+16,q+32,q+48} = 32 keys of q
    float tmax = sacc[0][0];
#pragma unroll
    for (int kt = 0; kt < 2; ++kt)
#pragma unroll
      for (int r = 0; r < 4; ++r) tmax = fmaxf(tmax, sacc[kt][r]);
    tmax = fmaxf(tmax, __shfl_xor(tmax, 16));
    tmax = fmaxf(tmax, __shfl_xor(tmax, 32));
    if (!__all(tmax <= m_run + 8.0f)) {
      float mnew = fmaxf(m_run, tmax);
      float alpha = __expf(m_run - mnew);
      l_run *= alpha;
#pragma unroll
      for (int dt = 0; dt < 4; ++dt)
#pragma unroll
        for (int j = 0; j < 4; ++j) ctx[dt][j] *= alpha;
      m_run = mnew;
    }
    float ps = 0.f;
    __bf16* pw = &spl[wid][0];
#pragma unroll
    for (int kt = 0; kt < 2; ++kt) {
      bf16x4 pv4;
#pragma unroll
      for (int r = 0; r < 4; ++r) {
        float p = __expf(sacc[kt][r] - m_run);
        ps += p;
        pv4[r] = (__bf16)p;
      }
      *(bf16x4*)(pw + l15 * 40 + kt * 16 + lq * 4) = pv4;  // P[q][key]
    }
    l_run += ps;

    asm volatile("s_waitcnt lgkmcnt(0)" ::: "memory");  // P visible within wave
    bf16x8 pa = *(const bf16x8*)(pw + l15 * 40 + lq * 8);  // B-frag: P[q=l15][k=8*lq+i]

    __builtin_amdgcn_s_setprio(1);
#pragma unroll
    for (int dt = 0; dt < 4; ++dt) {
      int d = dt * 16 + l15;
      int off = d * 32 + (lq ^ ((d >> 1) & 3)) * 8;  // swizzled read
      bf16x8 vhf = *(const bf16x8*)(&svh[cur][0] + off);
      bf16x8 vlf = *(const bf16x8*)(&svl[cur][0] + off);
      ctx[dt] = MFMA(vhf, pa, ctx[dt]);  // ctx^T[d][q]
      ctx[dt] = MFMA(vlf, pa, ctx[dt]);
    }
    __builtin_amdgcn_s_setprio(0);
    __syncthreads();
  }

  l_run += __shfl_xor(l_run, 16);
  l_run += __shfl_xor(l_run, 32);
  float inv = 1.f / l_run;
  int row = qbase + l15;
#pragma unroll
  for (int dt = 0; dt < 4; ++dt)
#pragma unroll
    for (int r = 0; r < 4; ++r) {
      float v = ctx[dt][r] * inv;
      int col = h * 64 + dt * 16 + lq * 4 + r;
      __bf16 hb = (__bf16)v;
      Cxh[(size_t)row * 1024 + col] = hb;
      Cxl[(size_t)row * 1024 + col] = (__bf16)(v - (float)hb);
    }
}

// ---------------- 5. output projection (64x128 tiles, 256 blocks) ----------------
__global__ __launch_bounds__(256) void proj_kernel(
    char* __restrict__ ws, const float* __restrict__ bo, float* __restrict__ out) {
  __shared__ __align__(16) __bf16 smem[2][12288];  // 48 KB
  gemm_core<64, 128, 2>(&smem[0][0], (const __bf16*)(ws + O_CXH), (const __bf16*)(ws + O_CXL),
                        (const __bf16*)(ws + O_WOH), (const __bf16*)(ws + O_WOL), bo, 1.0f,
                        nullptr, nullptr, out, blockIdx.x, blockIdx.y);
}

extern "C" void kernel_launch(void* const* d_in, const int* in_sizes, int n_in,
                              void* d_out, int out_size, void* d_ws, size_t ws_size,
                              hipStream_t stream) {
  const float* x  = (const float*)d_in[0];
  const float* Wq = (const float*)d_in[1];
  const float* bq = (const float*)d_in[2];
  const float* Wk = (const float*)d_in[3];
  const float* bk = (const float*)d_in[4];
  const float* Wv = (const float*)d_in[5];
  const float* bv = (const float*)d_in[6];
  const float* Wo = (const float*)d_in[7];
  const float* bo = (const float*)d_in[8];
  char* ws = (char*)d_ws;
  float* out = (float*)d_out;

  // 1. split x (2048*1024 elems / 4 per thread)
  split_kernel<<<2048, 256, 0, stream>>>(x, (__bf16*)(ws + O_XHI), (__bf16*)(ws + O_XLO));
  // 2. transpose-split all 4 weights in one launch
  tsplit_kernel<<<dim3(32, 32, 4), 256, 0, stream>>>(ws, Wq, Wk, Wv, Wo);
  // 3. fused QKV (z: 0=Q scaled, 1=K, 2=V transposed), 128x128 tiles
  qkv_kernel<<<dim3(16, 8, 3), 256, 0, stream>>>(ws, bq, bk, bv);
  // 4. flash attention
  attn_kernel<<<dim3(32, 16), 256, 0, stream>>>(ws);
  // 5. projection, 64x128 tiles
  proj_kernel<<<dim3(32, 8), 256, 0, stream>>>(ws, bo, out);
}

// Round 4
// 216.367 us; speedup vs baseline: 1.0794x; 1.0794x over previous
//
#include <hip/hip_runtime.h>
#include <hip/hip_bf16.h>
#include <math.h>

// BertSelfAttention on MI355X (gfx950).
// S=2048, H=1024, 16 heads, hd=64. fp32 in/out, bf16x3-split MFMA compute.
//
// R3 changes vs R2:
//  - ALL hot loops: counted-vmcnt pipeline (T3+T4). Per iter:
//      lgkmcnt(0); s_barrier; stage(k+1); vmcnt(LOADS); s_barrier; sched_barrier; compute
//    -> next tile's loads stay in flight across compute (no vmcnt(0) drain; was
//       ~2400 stall cyc/iter hidden barrier drain via __syncthreads).
//  - attn: back to KBLK=64 (32 iters; R2's KBLK=32 doubled barrier count = regression),
//    LDS 69KB (grid caps occupancy at 2 blocks/CU anyway), 8-seg K/V swizzle.
//  - proj: 64x64 tiles, 512 blocks -> 2 blocks/CU (was 1).
//
#define MB(x) ((size_t)(x) << 20)
static constexpr size_t O_XHI = MB(0),  O_XLO = MB(4);
static constexpr size_t O_WQH = MB(8),  O_WQL = MB(10);
static constexpr size_t O_WKH = MB(12), O_WKL = MB(14);
static constexpr size_t O_WVH = MB(16), O_WVL = MB(18);
static constexpr size_t O_WOH = MB(20), O_WOL = MB(22);
static constexpr size_t O_QHI = MB(24), O_QLO = MB(28);
static constexpr size_t O_KHI = MB(32), O_KLO = MB(36);
static constexpr size_t O_VTH = MB(40), O_VTL = MB(44);  // V^T [1024][2048]
static constexpr size_t O_CXH = MB(48), O_CXL = MB(52);

typedef __bf16 bf16x8 __attribute__((ext_vector_type(8)));
typedef __bf16 bf16x4 __attribute__((ext_vector_type(4)));
typedef float  f32x4  __attribute__((ext_vector_type(4)));

#define MFMA(a, b, c) __builtin_amdgcn_mfma_f32_16x16x32_bf16(a, b, c, 0, 0, 0)

__device__ __forceinline__ void g2l16(const void* g, void* l) {
  __builtin_amdgcn_global_load_lds(
      (const __attribute__((address_space(1))) unsigned int*)g,
      (__attribute__((address_space(3))) unsigned int*)l, 16, 0, 0);
}

template <int N>
__device__ __forceinline__ void vmcnt_wait() {
  if constexpr (N == 0)      asm volatile("s_waitcnt vmcnt(0)" ::: "memory");
  else if constexpr (N == 4) asm volatile("s_waitcnt vmcnt(4)" ::: "memory");
  else if constexpr (N == 6) asm volatile("s_waitcnt vmcnt(6)" ::: "memory");
  else if constexpr (N == 8) asm volatile("s_waitcnt vmcnt(8)" ::: "memory");
}
__device__ __forceinline__ void lgkm0_barrier() {
  asm volatile("s_waitcnt lgkmcnt(0)" ::: "memory");
  __builtin_amdgcn_s_barrier();
}

// ---------------- 1. elementwise hi/lo split (x) ----------------
__global__ __launch_bounds__(256) void split_kernel(
    const float* __restrict__ s, __bf16* __restrict__ hi, __bf16* __restrict__ lo) {
  int i = blockIdx.x * 256 + threadIdx.x;
  float4 v = reinterpret_cast<const float4*>(s)[i];
  float vv[4] = {v.x, v.y, v.z, v.w};
  bf16x4 h, l;
#pragma unroll
  for (int j = 0; j < 4; ++j) {
    __bf16 hb = (__bf16)vv[j];
    h[j] = hb;
    l[j] = (__bf16)(vv[j] - (float)hb);
  }
  reinterpret_cast<bf16x4*>(hi)[i] = h;
  reinterpret_cast<bf16x4*>(lo)[i] = l;
}

// ---------------- 2. transpose + hi/lo split (4 weights, 1024x1024) ----------------
__global__ __launch_bounds__(256) void tsplit_kernel(
    char* __restrict__ ws, const float* __restrict__ W0, const float* __restrict__ W1,
    const float* __restrict__ W2, const float* __restrict__ W3) {
  const float* srcs[4] = {W0, W1, W2, W3};
  const size_t hofs[4] = {O_WQH, O_WKH, O_WVH, O_WOH};
  const size_t lofs[4] = {O_WQL, O_WKL, O_WVL, O_WOL};
  int z = blockIdx.z;
  const float* s = srcs[z];
  __bf16* thi = (__bf16*)(ws + hofs[z]);
  __bf16* tlo = (__bf16*)(ws + lofs[z]);
  __shared__ float tile[32][33];
  int tx = threadIdx.x & 31, ty = threadIdx.x >> 5;  // 32x8
  int r0 = blockIdx.y * 32, c0 = blockIdx.x * 32;
#pragma unroll
  for (int j = 0; j < 32; j += 8)
    tile[ty + j][tx] = s[(size_t)(r0 + ty + j) * 1024 + c0 + tx];
  __syncthreads();
#pragma unroll
  for (int j = 0; j < 32; j += 8) {
    float v = tile[tx][ty + j];
    __bf16 hb = (__bf16)v;
    size_t o = (size_t)(c0 + ty + j) * 1024 + r0 + tx;  // out[c][r] = in[r][c]
    thi[o] = hb;
    tlo[o] = (__bf16)(v - (float)hb);
  }
}

// ---------------- GEMM core: C[M,N] = A[M,1024] @ Bt[N,1024]^T + bias ----------------
// BK=32, 256 threads = 4 waves (2x2), double-buffered with counted-vmcnt pipeline.
// bf16x3: acc += Ahi*Bhi + Alo*Bhi + Ahi*Blo.
// Buffer layout (elems): sAh=0 [BM][32], sAl=BM*32, sBh=BM*64 [BN][32], sBl=BM*64+BN*32.
// LDS 16B-seg swizzle: LDS[row][seg s] holds global seg s^((row>>1)&3).
template <int BM, int BN>
__device__ __forceinline__ void stage_gemm(
    const __bf16* __restrict__ Ahi, const __bf16* __restrict__ Alo,
    const __bf16* __restrict__ Bth, const __bf16* __restrict__ Btl,
    __bf16* buf, int t, size_t abase, size_t bbase, int k0) {
#pragma unroll
  for (int i = 0; i < BM / 64; ++i) {
    g2l16(Ahi + abase + (size_t)i * 64 * 1024 + k0, buf + i * 2048 + (size_t)t * 8);
    g2l16(Alo + abase + (size_t)i * 64 * 1024 + k0, buf + BM * 32 + i * 2048 + (size_t)t * 8);
  }
#pragma unroll
  for (int i = 0; i < BN / 64; ++i) {
    g2l16(Bth + bbase + (size_t)i * 64 * 1024 + k0, buf + BM * 64 + i * 2048 + (size_t)t * 8);
    g2l16(Btl + bbase + (size_t)i * 64 * 1024 + k0, buf + BM * 64 + BN * 32 + i * 2048 + (size_t)t * 8);
  }
}

template <int BM, int BN, int MODE>
__device__ __forceinline__ void gemm_core(
    __bf16* smem,  // [2][(BM+BN)*64]
    const __bf16* __restrict__ Ahi, const __bf16* __restrict__ Alo,
    const __bf16* __restrict__ Bth, const __bf16* __restrict__ Btl,
    const float* __restrict__ bias, float scale,
    __bf16* __restrict__ Ohi, __bf16* __restrict__ Olo, float* __restrict__ Of,
    int bm, int bn) {
  constexpr int MT = BM / 32, NT = BN / 32;
  constexpr int BUF = (BM + BN) * 64;
  constexpr int LOADS = (BM / 64 + BN / 64) * 2;
  const int t = threadIdx.x;
  const int lane = t & 63, wid = t >> 6;
  const int wm = wid >> 1, wn = wid & 1;
  const int l15 = lane & 15, lq = lane >> 4;

  f32x4 acc[MT][NT];
#pragma unroll
  for (int i = 0; i < MT; ++i)
#pragma unroll
    for (int j = 0; j < NT; ++j) acc[i][j] = f32x4{0.f, 0.f, 0.f, 0.f};

  const int sg = (t & 3) ^ ((t >> 3) & 3);  // pre-swizzled global 16B seg
  const size_t abase = (size_t)(bm * BM + (t >> 2)) * 1024 + sg * 8;
  const size_t bbase = (size_t)(bn * BN + (t >> 2)) * 1024 + sg * 8;

  stage_gemm<BM, BN>(Ahi, Alo, Bth, Btl, smem, t, abase, bbase, 0);

  for (int ks = 0; ks < 32; ++ks) {
    __bf16* cur = smem + (size_t)(ks & 1) * BUF;
    if (ks) lgkm0_barrier();  // all waves done reading buf[(ks+1)&1] (iter ks-1)
    if (ks + 1 < 32) {
      stage_gemm<BM, BN>(Ahi, Alo, Bth, Btl, smem + (size_t)((ks + 1) & 1) * BUF,
                         t, abase, bbase, (ks + 1) * 32);
      vmcnt_wait<LOADS>();  // own stage(ks) loads landed; stage(ks+1) stays in flight
    } else {
      vmcnt_wait<0>();
    }
    __builtin_amdgcn_s_barrier();  // everyone's stage(ks) landed
    __builtin_amdgcn_sched_barrier(0);

    bf16x8 bh[NT], bl[NT];
#pragma unroll
    for (int nt = 0; nt < NT; ++nt) {
      int row = wn * (NT * 16) + nt * 16 + l15;
      int off = row * 32 + (lq ^ ((row >> 1) & 3)) * 8;
      bh[nt] = *(const bf16x8*)(cur + BM * 64 + off);
      bl[nt] = *(const bf16x8*)(cur + BM * 64 + BN * 32 + off);
    }
#pragma unroll
    for (int mt = 0; mt < MT; ++mt) {
      int row = wm * (MT * 16) + mt * 16 + l15;
      int off = row * 32 + (lq ^ ((row >> 1) & 3)) * 8;
      bf16x8 ah = *(const bf16x8*)(cur + off);
      bf16x8 al = *(const bf16x8*)(cur + BM * 32 + off);
      __builtin_amdgcn_s_setprio(1);
#pragma unroll
      for (int nt = 0; nt < NT; ++nt) {
        acc[mt][nt] = MFMA(ah, bh[nt], acc[mt][nt]);
        acc[mt][nt] = MFMA(al, bh[nt], acc[mt][nt]);
        acc[mt][nt] = MFMA(ah, bl[nt], acc[mt][nt]);
      }
      __builtin_amdgcn_s_setprio(0);
    }
  }

#pragma unroll
  for (int nt = 0; nt < NT; ++nt) {
    int col = bn * BN + wn * (NT * 16) + nt * 16 + l15;
    float bv = bias[col];
#pragma unroll
    for (int mt = 0; mt < MT; ++mt) {
#pragma unroll
      for (int r = 0; r < 4; ++r) {
        int row = bm * BM + wm * (MT * 16) + mt * 16 + lq * 4 + r;
        float v = (acc[mt][nt][r] + bv) * scale;
        if constexpr (MODE == 0) {
          __bf16 hb = (__bf16)v;
          Ohi[(size_t)row * 1024 + col] = hb;
          Olo[(size_t)row * 1024 + col] = (__bf16)(v - (float)hb);
        } else if constexpr (MODE == 1) {
          __bf16 hb = (__bf16)v;
          Ohi[(size_t)col * 2048 + row] = hb;
          Olo[(size_t)col * 2048 + row] = (__bf16)(v - (float)hb);
        } else {
          Of[(size_t)row * 1024 + col] = v;
        }
      }
    }
  }
}

// ---------------- 3. fused QKV (128x128 tiles) ----------------
__global__ __launch_bounds__(256) void qkv_kernel(
    char* __restrict__ ws, const float* __restrict__ bq,
    const float* __restrict__ bk, const float* __restrict__ bv) {
  __shared__ __align__(16) __bf16 smem[2][16384];  // 64 KB
  const __bf16* xhi = (const __bf16*)(ws + O_XHI);
  const __bf16* xlo = (const __bf16*)(ws + O_XLO);
  int bm = blockIdx.x, bn = blockIdx.y;
  if (blockIdx.z == 0) {
    gemm_core<128, 128, 0>(&smem[0][0], xhi, xlo, (const __bf16*)(ws + O_WQH),
                           (const __bf16*)(ws + O_WQL), bq, 0.125f,
                           (__bf16*)(ws + O_QHI), (__bf16*)(ws + O_QLO), nullptr, bm, bn);
  } else if (blockIdx.z == 1) {
    gemm_core<128, 128, 0>(&smem[0][0], xhi, xlo, (const __bf16*)(ws + O_WKH),
                           (const __bf16*)(ws + O_WKL), bk, 1.0f,
                           (__bf16*)(ws + O_KHI), (__bf16*)(ws + O_KLO), nullptr, bm, bn);
  } else {
    gemm_core<128, 128, 1>(&smem[0][0], xhi, xlo, (const __bf16*)(ws + O_WVH),
                           (const __bf16*)(ws + O_WVL), bv, 1.0f,
                           (__bf16*)(ws + O_VTH), (__bf16*)(ws + O_VTL), nullptr, bm, bn);
  }
}

// ---------------- 4. flash attention ----------------
// grid (32 qblocks, 16 heads), 256 thr = 4 waves; wave owns 16 queries; KBLK=64.
// K tile [64 keys][64 d], V^T tile [64 d][64 k]; 8-seg XOR swizzle (seg^(row&7)).
// Counted-vmcnt pipeline; 32 iters.
__device__ __forceinline__ void stage_attn(
    const __bf16* __restrict__ Khi, const __bf16* __restrict__ Klo,
    const __bf16* __restrict__ Vth, const __bf16* __restrict__ Vtl,
    __bf16* kh, __bf16* kl, __bf16* vh, __bf16* vl, int t, int h, int kb) {
  const int tr = t >> 3;                 // tile row 0..31 (also +32)
  const int sg = (t & 7) ^ (tr & 7);     // pre-swizzled 16B seg (8 segs/row)
  const size_t kg = (size_t)(kb * 64 + tr) * 1024 + h * 64 + sg * 8;
  g2l16(Khi + kg, kh + (size_t)t * 8);
  g2l16(Khi + kg + (size_t)32 * 1024, kh + 2048 + (size_t)t * 8);
  g2l16(Klo + kg, kl + (size_t)t * 8);
  g2l16(Klo + kg + (size_t)32 * 1024, kl + 2048 + (size_t)t * 8);
  const size_t vg = (size_t)(h * 64 + tr) * 2048 + kb * 64 + sg * 8;
  g2l16(Vth + vg, vh + (size_t)t * 8);
  g2l16(Vth + vg + (size_t)32 * 2048, vh + 2048 + (size_t)t * 8);
  g2l16(Vtl + vg, vl + (size_t)t * 8);
  g2l16(Vtl + vg + (size_t)32 * 2048, vl + 2048 + (size_t)t * 8);
}

__global__ __launch_bounds__(256) void attn_kernel(char* __restrict__ ws) {
  __shared__ __align__(16) __bf16 skh[2][4096];  // [buf][64 keys][64 d] swizzled
  __shared__ __align__(16) __bf16 skl[2][4096];
  __shared__ __align__(16) __bf16 svh[2][4096];  // [buf][64 d][64 k] swizzled
  __shared__ __align__(16) __bf16 svl[2][4096];
  __shared__ __align__(16) __bf16 spl[4][16 * 72];  // per-wave P[16 q][72] (pad 64->72)

  const __bf16* Qhi = (const __bf16*)(ws + O_QHI);
  const __bf16* Qlo = (const __bf16*)(ws + O_QLO);
  const __bf16* Khi = (const __bf16*)(ws + O_KHI);
  const __bf16* Klo = (const __bf16*)(ws + O_KLO);
  const __bf16* Vth = (const __bf16*)(ws + O_VTH);
  const __bf16* Vtl = (const __bf16*)(ws + O_VTL);
  __bf16* Cxh = (__bf16*)(ws + O_CXH);
  __bf16* Cxl = (__bf16*)(ws + O_CXL);

  const int t = threadIdx.x, lane = t & 63, wid = t >> 6;
  const int l15 = lane & 15, lq = lane >> 4;
  const int h = blockIdx.y;
  const int qbase = blockIdx.x * 64 + wid * 16;

  // Q fragments hoisted (already scaled by 1/8): lane holds Q[q=l15][d=32*dc+8*lq+i]
  bf16x8 qh[2], ql[2];
  {
    const size_t qrow = (size_t)(qbase + l15) * 1024 + h * 64 + lq * 8;
    qh[0] = *(const bf16x8*)(Qhi + qrow);
    qh[1] = *(const bf16x8*)(Qhi + qrow + 32);
    ql[0] = *(const bf16x8*)(Qlo + qrow);
    ql[1] = *(const bf16x8*)(Qlo + qrow + 32);
  }

  f32x4 ctx[4];
#pragma unroll
  for (int i = 0; i < 4; ++i) ctx[i] = f32x4{0.f, 0.f, 0.f, 0.f};
  float m_run = -INFINITY, l_run = 0.f;

  stage_attn(Khi, Klo, Vth, Vtl, skh[0], skl[0], svh[0], svl[0], t, h, 0);

  for (int kb = 0; kb < 32; ++kb) {
    const int cur = kb & 1;
    if (kb) lgkm0_barrier();  // all waves done reading buf[(kb+1)&1] (iter kb-1)
    if (kb + 1 < 32) {
      const int nxt = cur ^ 1;
      stage_attn(Khi, Klo, Vth, Vtl, skh[nxt], skl[nxt], svh[nxt], svl[nxt], t, h, kb + 1);
      vmcnt_wait<8>();  // own stage(kb) landed; stage(kb+1) stays in flight
    } else {
      vmcnt_wait<0>();
    }
    __builtin_amdgcn_s_barrier();
    __builtin_amdgcn_sched_barrier(0);

    // ---- scores S^T [64 keys][16 q], bf16x3 over d=64 (2 chunks) ----
    f32x4 sacc[4];
    __builtin_amdgcn_s_setprio(1);
#pragma unroll
    for (int kt = 0; kt < 4; ++kt) {
      sacc[kt] = f32x4{0.f, 0.f, 0.f, 0.f};
#pragma unroll
      for (int dc = 0; dc < 2; ++dc) {
        int key = kt * 16 + l15;
        int off = key * 64 + ((dc * 4 + lq) ^ (key & 7)) * 8;  // swizzled read
        bf16x8 khf = *(const bf16x8*)(&skh[cur][0] + off);
        bf16x8 klf = *(const bf16x8*)(&skl[cur][0] + off);
        sacc[kt] = MFMA(khf, qh[dc], sacc[kt]);
        sacc[kt] = MFMA(klf, qh[dc], sacc[kt]);
        sacc[kt] = MFMA(khf, ql[dc], sacc[kt]);
      }
    }
    __builtin_amdgcn_s_setprio(0);

    // ---- online softmax (defer-max THR=8): lanes {q,q+16,q+32,q+48} = 64 keys of q
    float tmax = sacc[0][0];
#pragma unroll
    for (int kt = 0; kt < 4; ++kt)
#pragma unroll
      for (int r = 0; r < 4; ++r) tmax = fmaxf(tmax, sacc[kt][r]);
    tmax = fmaxf(tmax, __shfl_xor(tmax, 16));
    tmax = fmaxf(tmax, __shfl_xor(tmax, 32));
    if (!__all(tmax <= m_run + 8.0f)) {
      float mnew = fmaxf(m_run, tmax);
      float alpha = __expf(m_run - mnew);
      l_run *= alpha;
#pragma unroll
      for (int dt = 0; dt < 4; ++dt)
#pragma unroll
        for (int j = 0; j < 4; ++j) ctx[dt][j] *= alpha;
      m_run = mnew;
    }
    float ps = 0.f;
    __bf16* pw = &spl[wid][0];
#pragma unroll
    for (int kt = 0; kt < 4; ++kt) {
      bf16x4 pv4;
#pragma unroll
      for (int r = 0; r < 4; ++r) {
        float p = __expf(sacc[kt][r] - m_run);
        ps += p;
        pv4[r] = (__bf16)p;
      }
      *(bf16x4*)(pw + l15 * 72 + kt * 16 + lq * 4) = pv4;  // P[q][key]
    }
    l_run += ps;

    asm volatile("s_waitcnt lgkmcnt(0)" ::: "memory");  // P visible within wave
    __builtin_amdgcn_sched_barrier(0);

    __builtin_amdgcn_s_setprio(1);
#pragma unroll
    for (int kc = 0; kc < 2; ++kc) {
      bf16x8 pa = *(const bf16x8*)(pw + l15 * 72 + kc * 32 + lq * 8);  // P[q][k-chunk]
#pragma unroll
      for (int dt = 0; dt < 4; ++dt) {
        int d = dt * 16 + l15;
        int off = d * 64 + ((kc * 4 + lq) ^ (d & 7)) * 8;  // swizzled read
        bf16x8 vhf = *(const bf16x8*)(&svh[cur][0] + off);
        bf16x8 vlf = *(const bf16x8*)(&svl[cur][0] + off);
        ctx[dt] = MFMA(vhf, pa, ctx[dt]);  // ctx^T[d][q]
        ctx[dt] = MFMA(vlf, pa, ctx[dt]);
      }
    }
    __builtin_amdgcn_s_setprio(0);
  }

  l_run += __shfl_xor(l_run, 16);
  l_run += __shfl_xor(l_run, 32);
  float inv = 1.f / l_run;
  int row = qbase + l15;
#pragma unroll
  for (int dt = 0; dt < 4; ++dt)
#pragma unroll
    for (int r = 0; r < 4; ++r) {
      float v = ctx[dt][r] * inv;
      int col = h * 64 + dt * 16 + lq * 4 + r;
      __bf16 hb = (__bf16)v;
      Cxh[(size_t)row * 1024 + col] = hb;
      Cxl[(size_t)row * 1024 + col] = (__bf16)(v - (float)hb);
    }
}

// ---------------- 5. output projection (64x64 tiles, 512 blocks) ----------------
__global__ __launch_bounds__(256) void proj_kernel(
    char* __restrict__ ws, const float* __restrict__ bo, float* __restrict__ out) {
  __shared__ __align__(16) __bf16 smem[2][8192];  // 32 KB
  gemm_core<64, 64, 2>(&smem[0][0], (const __bf16*)(ws + O_CXH), (const __bf16*)(ws + O_CXL),
                       (const __bf16*)(ws + O_WOH), (const __bf16*)(ws + O_WOL), bo, 1.0f,
                       nullptr, nullptr, out, blockIdx.x, blockIdx.y);
}

extern "C" void kernel_launch(void* const* d_in, const int* in_sizes, int n_in,
                              void* d_out, int out_size, void* d_ws, size_t ws_size,
                              hipStream_t stream) {
  const float* x  = (const float*)d_in[0];
  const float* Wq = (const float*)d_in[1];
  const float* bq = (const float*)d_in[2];
  const float* Wk = (const float*)d_in[3];
  const float* bk = (const float*)d_in[4];
  const float* Wv = (const float*)d_in[5];
  const float* bv = (const float*)d_in[6];
  const float* Wo = (const float*)d_in[7];
  const float* bo = (const float*)d_in[8];
  char* ws = (char*)d_ws;
  float* out = (float*)d_out;

  // 1. split x (2048*1024 elems / 4 per thread)
  split_kernel<<<2048, 256, 0, stream>>>(x, (__bf16*)(ws + O_XHI), (__bf16*)(ws + O_XLO));
  // 2. transpose-split all 4 weights in one launch
  tsplit_kernel<<<dim3(32, 32, 4), 256, 0, stream>>>(ws, Wq, Wk, Wv, Wo);
  // 3. fused QKV (z: 0=Q scaled, 1=K, 2=V transposed), 128x128 tiles
  qkv_kernel<<<dim3(16, 8, 3), 256, 0, stream>>>(ws, bq, bk, bv);
  // 4. flash attention
  attn_kernel<<<dim3(32, 16), 256, 0, stream>>>(ws);
  // 5. projection, 64x64 tiles
  proj_kernel<<<dim3(32, 16), 256, 0, stream>>>(ws, bo, out);
}